// Round 2
// baseline (227.863 us; speedup 1.0000x reference)
//
#include <hip/hip_runtime.h>
#include <math.h>

#define BLOCK 256
#define WS_W2_F2 1024  // float2 index of W2 block inside ws (float offset 2048)

typedef float v2f __attribute__((ext_vector_type(2)));

__device__ __forceinline__ float fast_rcp(float v) {
  float r = __builtin_amdgcn_rcpf(v);
  r = r * (2.0f - v * r);  // 1 Newton step -> ~1 ulp
  return r;
}

// round(clip(v/step, lo, hi)) with exact IEEE division (used for weights, once)
__device__ __forceinline__ float quant_div(float v, float step, float lo, float hi) {
  float t = v / step;
  t = fminf(fmaxf(t, lo), hi);
  return rintf(t);
}

// Prepass: quantize weights to integer-valued floats in ws.
// ws[0..2047]   = qW1 transposed: qw1t[k*16 + j] = round(clip(W1[j,k]/wa1))
// ws[2048..2207]= qW2[j*16 + i]  = round(clip(W2[j,i]/wa2))
__global__ void prep_kernel(const float* __restrict__ W1, const float* __restrict__ wa1p,
                            const float* __restrict__ W2, const float* __restrict__ wa2p,
                            float* __restrict__ ws) {
  const int t = threadIdx.x;
  const float wa1 = wa1p[0], wa2 = wa2p[0];
  for (int e = t; e < 2048; e += BLOCK) {
    int k = e >> 4, j = e & 15;
    ws[e] = quant_div(W1[j * 128 + k], wa1, -128.0f, 127.0f);
  }
  if (t < 160) {
    ws[2048 + t] = quant_div(W2[t], wa2, -128.0f, 127.0f);
  }
}

template <bool USE_WS>
__global__ __launch_bounds__(BLOCK, 4)
void net_kernel(const float* __restrict__ x,
                const float* __restrict__ alpha_p, const float* __restrict__ beta_p,
                const float* __restrict__ a1p, const float* __restrict__ a2p,
                const float* __restrict__ a3p,
                const float* __restrict__ W1, const float* __restrict__ b1,
                const float* __restrict__ wa1p,
                const float* __restrict__ W2, const float* __restrict__ b2,
                const float* __restrict__ wa2p,
                const float* __restrict__ ws,
                float* __restrict__ out, int M) {
  __shared__ __align__(16) float smw[2208];
  const float* wsrc;
  if constexpr (USE_WS) {
    wsrc = ws;
  } else {
    // fallback: block-local weight quantize into LDS
    const int t = threadIdx.x;
    const float wa1 = wa1p[0], wa2 = wa2p[0];
    for (int e = t; e < 2048; e += BLOCK) {
      int k = e >> 4, j = e & 15;
      smw[e] = quant_div(W1[j * 128 + k], wa1, -128.0f, 127.0f);
    }
    if (t < 160) smw[2048 + t] = quant_div(W2[t], wa2, -128.0f, 127.0f);
    __syncthreads();
    wsrc = smw;
  }

  const int row = blockIdx.x * BLOCK + threadIdx.x;
  if (row >= M) return;

  const float alpha = alpha_p[0], beta = beta_p[0];
  const float a1 = a1p[0], a2 = a2p[0], a3 = a3p[0];
  const float wa1 = wa1p[0], wa2 = wa2p[0];
  const float inv_a1 = 1.0f / a1;  // IEEE once (same as round-1, which passed)
  const float inv_a2 = 1.0f / a2;
  const float inv_a3 = 1.0f / a3;
  const float scale1 = a1 * wa1;   // h = scale1 * (int dot) + b1   (dot exact in fp32)
  const float scale2 = a3 * wa2;   // out = scale2 * (int dot) + b2

  const float4* __restrict__ xr = (const float4*)(x + (size_t)row * 128);
  const v2f* __restrict__ wt2 = (const v2f*)wsrc;

  v2f acc2[8];
#pragma unroll
  for (int j = 0; j < 8; ++j) acc2[j] = (v2f)0.0f;

  // double-buffered 128 B x-bursts: prefetch next burst before computing current
  float4 buf[2][8];
#pragma unroll
  for (int u = 0; u < 8; ++u) buf[0][u] = xr[u];

  float w = 1.0f;
#pragma unroll
  for (int cc = 0; cc < 4; ++cc) {
    if (cc < 3) {
#pragma unroll
      for (int u = 0; u < 8; ++u) buf[(cc + 1) & 1][u] = xr[(cc + 1) * 8 + u];
    }
    const float* xs = (const float*)buf[cc & 1];
#pragma unroll
    for (int kk = 0; kk < 32; ++kk) {
      const int k = cc * 32 + kk;
      // q = round(clip(w/a1, -128, 127))  (integer-valued float)
      float t = w * inv_a1;
      t = fminf(fmaxf(t, -128.0f), 127.0f);
      const float q = rintf(t);
      const v2f qv = q;  // broadcast
      const v2f* __restrict__ wk = wt2 + k * 8;  // wave-uniform 64 B row (scalar-load eligible)
      // 8 packed fp32 FMAs (v_pk_fma_f32); products/sums are exact small ints -> bit-identical
#pragma unroll
      for (int u = 0; u < 8; ++u) acc2[u] = qv * wk[u] + acc2[u];
      // recurrence: w <- w + alpha/w - beta*x[k]   (errors contract: |dw'/dw| < 1)
      const float xk = xs[kk];
      const float r = fast_rcp(w);
      w = fmaf(alpha, r, w);
      w = fmaf(-beta, xk, w);
    }
  }

  const float* acc = (const float*)acc2;

  // epilogue: h -> sigmoid -> uq8 -> q8 (all per-lane, register-resident)
  float s3[16];
#pragma unroll
  for (int j = 0; j < 16; ++j) {
    const float h = fmaf(scale1, acc[j], b1[j]);
    const float e = expf(-h);
    const float s = fast_rcp(1.0f + e);
    float t2 = s * inv_a2;
    t2 = fminf(fmaxf(t2, 0.0f), 255.0f);
    const float s2 = rintf(t2) * a2;
    float t3 = s2 * inv_a3;
    t3 = fminf(fmaxf(t3, -128.0f), 127.0f);
    s3[j] = rintf(t3);  // integer-valued float
  }

  // fc2: out[j] = scale2 * sum_i q3[i]*qw2[j][i] + b2[j]  (exact int dot, any order)
  float oj[10];
#pragma unroll
  for (int j = 0; j < 10; ++j) {
    const v2f* __restrict__ u2 = wt2 + WS_W2_F2 + j * 8;
    v2f a = (v2f)0.0f;
#pragma unroll
    for (int i = 0; i < 8; ++i) {
      v2f sv;
      sv.x = s3[2 * i];
      sv.y = s3[2 * i + 1];
      a = sv * u2[i] + a;
    }
    oj[j] = fmaf(scale2, a.x + a.y, b2[j]);
  }
  v2f* __restrict__ orow2 = (v2f*)(out + (size_t)row * 10);  // 40 B offset -> 8 B aligned
#pragma unroll
  for (int j = 0; j < 5; ++j) {
    v2f o;
    o.x = oj[2 * j];
    o.y = oj[2 * j + 1];
    orow2[j] = o;
  }
}

extern "C" void kernel_launch(void* const* d_in, const int* in_sizes, int n_in,
                              void* d_out, int out_size, void* d_ws, size_t ws_size,
                              hipStream_t stream) {
  const float* x     = (const float*)d_in[0];
  const float* alpha = (const float*)d_in[1];
  const float* beta  = (const float*)d_in[2];
  const float* a1    = (const float*)d_in[3];
  const float* a2    = (const float*)d_in[4];
  const float* a3    = (const float*)d_in[5];
  const float* W1    = (const float*)d_in[6];
  const float* b1    = (const float*)d_in[7];
  const float* wa1   = (const float*)d_in[8];
  const float* W2    = (const float*)d_in[9];
  const float* b2    = (const float*)d_in[10];
  const float* wa2   = (const float*)d_in[11];
  float* out = (float*)d_out;
  const int M = in_sizes[0] / 128;
  const int grid = (M + BLOCK - 1) / BLOCK;
  if (ws_size >= 2208 * sizeof(float)) {
    float* ws = (float*)d_ws;
    prep_kernel<<<1, BLOCK, 0, stream>>>(W1, wa1, W2, wa2, ws);
    net_kernel<true><<<grid, BLOCK, 0, stream>>>(x, alpha, beta, a1, a2, a3,
                                                 W1, b1, wa1, W2, b2, wa2, ws, out, M);
  } else {
    net_kernel<false><<<grid, BLOCK, 0, stream>>>(x, alpha, beta, a1, a2, a3,
                                                  W1, b1, wa1, W2, b2, wa2, nullptr, out, M);
  }
}